// Round 2
// 65.930 us; speedup vs baseline: 1.0025x; 1.0025x over previous
//
#include <hip/hip_runtime.h>
#include <math.h>

#define IMGW 147
#define PI_F 3.14159265358979323846f
#define TWO_PI_F 6.28318530717958647692f
#define INV_TWO_PI_F 0.15915494309189533577f
#define INV_PI_F 0.31830988618379067154f
#define TAU_F 0.1f

// jnp.mod(x, 2pi) = x - floor(x/2pi)*2pi
__device__ __forceinline__ float mod2pi(float x) {
    float t = floorf(x * INV_TWO_PI_F);
    return fmaf(-t, TWO_PI_F, x);
}

// (dtheta/PI - 1)^35
__device__ __forceinline__ float gpow35(float dtheta) {
    float t = dtheta * INV_PI_F - 1.f;
    float t2 = t * t;
    float t4 = t2 * t2;
    float t8 = t4 * t4;
    float t16 = t8 * t8;
    float t32 = t16 * t16;
    return t32 * t2 * t;
}

// h = 0.5 + atan(z)/pi with z pre-scaled (z = 100*d baked into coefficients).
// degree-7 minimax atan on [0,1] + rcp fold; |h err| <= 3.2e-5.
__device__ __forceinline__ float fast_h_z(float z) {
    float az = fabsf(z);
    bool big = az > 1.0f;
    float r = big ? __builtin_amdgcn_rcpf(az) : az;
    float a = r * r;
    float pol = r * fmaf(a, fmaf(a, fmaf(a, -0.0851330f, 0.1801410f), -0.3302995f),
                         0.9998660f);
    float res = big ? (1.5707963267948966f - pol) : pol;
    res = copysignf(res, z);
    return fmaf(res, INV_PI_F, 0.5f);
}

// DPP tree-sum: full-wave sum lands in lane 63. VALU-only (no DS pipe).
// ctrl must be a literal -> template parameter.
template <int CTRL>
__device__ __forceinline__ float dpp_add(float x) {
    int y = __builtin_amdgcn_update_dpp(0, __float_as_int(x), CTRL, 0xf, 0xf, true);
    return x + __int_as_float(y);
}
__device__ __forceinline__ float wave_sum63(float x) {
    x = dpp_add<0x111>(x);   // row_shr:1
    x = dpp_add<0x112>(x);   // row_shr:2
    x = dpp_add<0x114>(x);   // row_shr:4
    x = dpp_add<0x118>(x);   // row_shr:8  -> lanes 15/31/47/63 hold row sums
    x = dpp_add<0x142>(x);   // row_bcast:15
    x = dpp_add<0x143>(x);   // row_bcast:31 -> lane 63 holds wave sum
    return x;
}

__global__ __launch_bounds__(256, 6) void wedge_colors_kernel(
    const float* __restrict__ ests,   // (4096, 5)
    const float* __restrict__ img,    // (147, 147, 3) HWC
    float* __restrict__ out)          // (3, 3, 64, 64)
{
    const int wave = threadIdx.x >> 6;
    const int lane = threadIdx.x & 63;
    const int half = wave & 1;        // which k-range this wave covers
    const int pp   = wave >> 1;       // pixel slot within block (0..1)
    const int p    = blockIdx.x * 2 + pp;   // pixel 0..4095
    const int ph   = p >> 6;
    const int pw   = p & 63;

    // partial-sum exchange between the two waves of a pixel.
    // word stride 11 (coprime with 32) -> max 2 lanes/bank = conflict-free.
    __shared__ float red[2][64][11];

    // ---- per-pixel setup (wave-uniform; duplicated across the 2 waves) ----
    const float* e = ests + p * 5;
    float b0 = mod2pi((e[0] + 1.f) * PI_F);
    float b1 = mod2pi((e[1] + 1.f) * PI_F);
    float b2 = mod2pi((e[2] + 1.f) * PI_F);
    float a1 = fminf(b0, fminf(b1, b2));
    float a3 = fmaxf(b0, fmaxf(b1, b2));
    float a2 = fmaxf(fminf(b0, b1), fminf(fmaxf(b0, b1), b2));  // exact median
    float x0 = e[3] * 3.f;
    float y0 = e[4] * 3.f;

    float mhalf = mod2pi(0.5f * (a1 - a3));
    float a4 = 0.5f * (a1 + a3) + (mhalf >= PI_F ? PI_F : 0.f);

    float d42m = mod2pi(a2 - a4);
    float d13m = mod2pi(a3 - a1);
    float sgn42 = (d42m < PI_F) ? 1.f : -1.f;
    float sgn13 = (d13m < PI_F) ? 1.f : -1.f;
    float g13z = gpow35(d13m) * (TAU_F * 100.f);   // x100 pre-scaled
    float g42z = gpow35(d42m) * (TAU_F * 100.f);

    float s1 = __sinf(a1), c1 = __cosf(a1);
    float s2 = __sinf(a2), c2 = __cosf(a2);
    float s3 = __sinf(a3), c3 = __cosf(a3);
    float s4 = __sinf(a4), c4 = __cosf(a4);

    // ---- per-lane invariants: lane -> (r_off = lane/21, col = lane%21) ----
    const int r_off = lane / 21;                  // 0..3 (3 for idle lane 63)
    const int s     = lane - 21 * r_off;          // 0..20
    float x  = (float)s * 0.1f - 1.f;
    float dx = x - x0;

    // sign-folded line coefficients, pre-scaled by 100 (feeds fast_h_z directly)
    float P1 = (sgn13 * c1) * 100.f, B1 = (-sgn13 * s1 * dx) * 100.f;
    float P3 = (-sgn13 * c3) * 100.f, B3 = (sgn13 * s3 * dx) * 100.f;
    float P4 = (sgn42 * c4) * 100.f, B4 = (-sgn42 * s4 * dx) * 100.f;
    float P2 = (-sgn42 * c2) * 100.f, B2 = (sgn42 * s2 * dx) * 100.f;

    // acc[0..2]=sum(p), acc[3..5]=sum(p*h0), acc[6..8]=sum(p*h0*h1),
    // acc[9]=sum(h0), acc[10]=sum(h0*h1)
    float acc[11];
#pragma unroll
    for (int q = 0; q < 11; q++) acc[q] = 0.f;

    if (lane < 63) {
        const float* base = img + ((2 * ph + r_off) * IMGW + (2 * pw + s)) * 3;

#define BODY(K) {                                                         \
        const float* px = base + (K) * (3 * IMGW * 3);                    \
        float p0 = px[0], p1 = px[1], p2 = px[2];                         \
        float yy = (float)(r_off + 3 * (K)) * 0.1f - 1.f;                 \
        float dy = yy - y0;                                               \
        float t1 = fmaf(P1, dy, B1);                                      \
        float t3 = fmaf(P3, dy, B3);                                      \
        float t4 = fmaf(P4, dy, B4);                                      \
        float t2 = fmaf(P2, dy, B2);                                      \
        float z13 = fmaf(sgn13, fminf(t1, t3), g13z);                     \
        float z42 = fmaf(sgn42, fminf(t4, t2), g42z);                     \
        float h0 = fast_h_z(z13);                                         \
        float h1 = fast_h_z(z42);                                         \
        float u  = h0 * h1;                                               \
        acc[0] += p0; acc[1] += p1; acc[2] += p2;                         \
        acc[3] = fmaf(p0, h0, acc[3]);                                    \
        acc[4] = fmaf(p1, h0, acc[4]);                                    \
        acc[5] = fmaf(p2, h0, acc[5]);                                    \
        acc[6] = fmaf(p0, u, acc[6]);                                     \
        acc[7] = fmaf(p1, u, acc[7]);                                     \
        acc[8] = fmaf(p2, u, acc[8]);                                     \
        acc[9] += h0; acc[10] += u; }

        if (half == 0) { BODY(0) BODY(1) BODY(2) BODY(3) }
        else           { BODY(4) BODY(5) BODY(6) }
#undef BODY
    }

    // ---- cross-wave lane-wise combine (same lane->sample map in both waves) ----
    if (half) {
#pragma unroll
        for (int q = 0; q < 11; q++) red[pp][lane][q] = acc[q];
    }
    __syncthreads();

    if (!half) {
#pragma unroll
        for (int q = 0; q < 11; q++) acc[q] += red[pp][lane][q];

        // ---- DPP tree reduction (VALU-only), totals land in lane 63 ----
#pragma unroll
        for (int q = 0; q < 11; q++) acc[q] = wave_sum63(acc[q]);

        if (lane == 63) {
            float sh = acc[9], su = acc[10];
            float inv0 = 1.f / (441.f - sh + 1e-10f);
            float inv1 = 1.f / (sh - su + 1e-10f);
            float inv2 = 1.f / (su + 1e-10f);
            const int base = ph * 64 + pw;
            out[0 * 4096 + base] = (acc[0] - acc[3]) * inv0;
            out[1 * 4096 + base] = (acc[3] - acc[6]) * inv1;
            out[2 * 4096 + base] = acc[6] * inv2;
            out[3 * 4096 + base] = (acc[1] - acc[4]) * inv0;
            out[4 * 4096 + base] = (acc[4] - acc[7]) * inv1;
            out[5 * 4096 + base] = acc[7] * inv2;
            out[6 * 4096 + base] = (acc[2] - acc[5]) * inv0;
            out[7 * 4096 + base] = (acc[5] - acc[8]) * inv1;
            out[8 * 4096 + base] = acc[8] * inv2;
        }
    }
}

extern "C" void kernel_launch(void* const* d_in, const int* in_sizes, int n_in,
                              void* d_out, int out_size, void* d_ws, size_t ws_size,
                              hipStream_t stream) {
    const float* ests  = (const float*)d_in[0];   // (1, 4096, 5)
    const float* noisy = (const float*)d_in[1];   // (1, 147, 147, 3)
    float* out = (float*)d_out;                   // (1, 3, 3, 64, 64)

    wedge_colors_kernel<<<2048, 256, 0, stream>>>(ests, noisy, out);
}